// Round 9
// baseline (9370.019 us; speedup 1.0000x reference)
//
#include <hip/hip_runtime.h>
#include <math.h>

#define DD 128
#define HH 256
#define NS 300
#define BB 512
#define NBLK 256   // rollout blocks (2 rows each)
#define TPB 512
#define NPO (301*64)

// Dynamic-LDS float offsets for k_rollout
#define OFF_W1Q 0        // 32768 floats: [k4 0..31][hj 0..255] as float4
#define OFF_XS  32768    // [2][128]
#define OFF_HS  33024    // [2][256]
#define OFF_WV  33536    // [2][128]
#define OFF_NOI 33792    // [2][128]
#define OFF_NVU 34048    // [2][128] (general path)
#define OFF_SCR 34304    // 6144 floats phase-shared partials
#define OFF_RED 40448    // 16
#define SMEM_FLOATS 40464
#define SMEM_BYTES (SMEM_FLOATS*4)   // 158.1 KB < 160 KB

__device__ __forceinline__ float tsf(int t){ return (float)((double)t*(1.0/(double)NS)); }

__device__ __forceinline__ float wave_red(float v){
#pragma unroll
  for(int o=32;o>0;o>>=1) v += __shfl_down(v,o);
  return v;
}
__device__ __forceinline__ float fma4(float4 a, float4 b, float acc){
  acc = fmaf(a.x,b.x,acc); acc = fmaf(a.y,b.y,acc);
  acc = fmaf(a.z,b.z,acc); acc = fmaf(a.w,b.w,acc); return acc;
}
__device__ __forceinline__ float4 fma_s4(float s, float4 w, float4 a){
  a.x = fmaf(s,w.x,a.x); a.y = fmaf(s,w.y,a.y);
  a.z = fmaf(s,w.z,a.z); a.w = fmaf(s,w.w,a.w); return a;
}

// ---- pre1: identity flag + (general) Gauss-Jordan inverse -> SIT = sigma^-T
__global__ __launch_bounds__(256) void k_pre1(
    const float* __restrict__ sigma,
    float* __restrict__ SIT, float* __restrict__ AUG, int* __restrict__ FLG)
{
  const int j = threadIdx.x;
  __shared__ int s_ok; __shared__ int s_p; __shared__ float s_fac[DD];
  if (j == 0) s_ok = 1;
  __syncthreads();
  bool ok = true;
  for (int idx = j; idx < DD*DD; idx += 256) {
    const int r = idx >> 7, c = idx & 127;
    if (sigma[idx] != (r==c ? 1.f : 0.f)) ok = false;
  }
  if (!ok) s_ok = 0;
  __syncthreads();
  const bool ident = (s_ok != 0);
  if (j == 0) *FLG = ident ? 1 : 0;
  if (ident) {
    for (int idx = j; idx < DD*DD; idx += 256) {
      const int r = idx >> 7, c = idx & 127;
      SIT[idx] = (r==c) ? 1.f : 0.f;
    }
    return;
  }
  for (int idx = j; idx < DD*256; idx += 256) {
    const int r = idx >> 8, c = idx & 255;
    AUG[idx] = (c < DD) ? sigma[r*DD + c] : ((c-DD)==r ? 1.f : 0.f);
  }
  __syncthreads();
  for (int c = 0; c < DD; ++c) {
    if (j == 0) {
      int p = c; float best = fabsf(AUG[c*256 + c]);
      for (int r2 = c+1; r2 < DD; ++r2) {
        const float v = fabsf(AUG[r2*256 + c]);
        if (v > best) { best = v; p = r2; }
      }
      s_p = p;
    }
    __syncthreads();
    const int p = s_p;
    if (p != c) {
      const float tmp = AUG[c*256 + j];
      AUG[c*256 + j] = AUG[p*256 + j];
      AUG[p*256 + j] = tmp;
    }
    __syncthreads();
    const float pd = AUG[c*256 + c];
    const float rowv = AUG[c*256 + j];
    __syncthreads();
    AUG[c*256 + j] = rowv / pd;
    if (j < DD) s_fac[j] = (j == c) ? 0.f : AUG[j*256 + c];
    __syncthreads();
    const float prj = AUG[c*256 + j];
    for (int r2 = 0; r2 < DD; ++r2) {
      if (r2 != c) AUG[r2*256 + j] -= s_fac[r2] * prj;
    }
    __syncthreads();
  }
  for (int idx = j; idx < DD*DD; idx += 256) {
    const int j2 = idx >> 7, k = idx & 127;
    SIT[idx] = AUG[k*256 + DD + j2];
  }
}

// ---- pre2: transposes AT/PT/QT/SGT ([k][i] = src[i][k]), M2T, SGC
__global__ __launch_bounds__(256) void k_pre2(
    const float* __restrict__ A, const float* __restrict__ P,
    const float* __restrict__ Q, const float* __restrict__ sigma,
    const float* __restrict__ SIT, const int* __restrict__ FLG,
    float* __restrict__ ATm, float* __restrict__ PTm,
    float* __restrict__ QTm, float* __restrict__ SGTm,
    float* __restrict__ M2T, float* __restrict__ SGC)
{
  const int g = blockIdx.x*256 + threadIdx.x;
  const int gs = gridDim.x*256;
  const bool ident = (*FLG != 0);
  for (int idx = g; idx < DD*DD; idx += gs) {
    const int k = idx >> 7, i2 = idx & 127;   // dest [k][i2]
    ATm[idx]  = A[i2*DD + k];
    PTm[idx]  = P[i2*DD + k];
    QTm[idx]  = Q[i2*DD + k];
    SGTm[idx] = sigma[i2*DD + k];
  }
  for (int idx = g; idx < DD*DD; idx += gs) {
    const int i2 = idx >> 7, k = idx & 127;
    SGC[idx] = sigma[k*DD + i2];
  }
  for (int idx = g; idx < DD*DD; idx += gs) {
    const int k = idx >> 7, i2 = idx & 127;
    float m;
    if (ident) m = -A[i2*DD + k];
    else {
      float acc = 0.f;
      for (int j = 0; j < DD; ++j) acc = fmaf(A[i2*DD + j], SIT[j*DD + k], acc);
      m = -acc;
    }
    M2T[idx] = m;
  }
}

// ---- rollout: 256 blocks x 512 threads, 2 rows/block, wave-specialized.
// Waves 0-3: MLP (W1 from LDS, full per-thread dots, fused tanh; W2 streamed).
// Waves 4-7: noise + AT/PT streamed matvecs, running CONCURRENTLY with MLP.
// All inline loads (no register arrays -> no spill at the 128-VGPR budget).
__global__ __launch_bounds__(TPB) void k_rollout(
    const float* __restrict__ x0, const float* __restrict__ sigma,
    const float* __restrict__ W1, const float* __restrict__ b1,
    const float* __restrict__ W2, const float* __restrict__ b2,
    const float* __restrict__ noises,
    const float* __restrict__ AT, const float* __restrict__ PT,
    const float* __restrict__ QT, const float* __restrict__ SGT,
    const float* __restrict__ M2T, const int* __restrict__ FLG,
    float* __restrict__ U, float* __restrict__ TL,
    float* __restrict__ TGT, float* __restrict__ WGT)
{
  extern __shared__ float sm[];
  float4* W1q = (float4*)(sm + OFF_W1Q);
  float*  xs  = sm + OFF_XS;
  float*  hs  = sm + OFF_HS;
  float*  wv  = sm + OFF_WV;
  float*  noi = sm + OFF_NOI;
  float*  nvu = sm + OFF_NVU;
  float*  scr = sm + OFF_SCR;
  float*  red = sm + OFF_RED;
  float4* xs4 = (float4*)xs;
  float4* scr4 = (float4*)scr;

  const int tid = threadIdx.x;
  const int i  = tid & 127;
  const int kq16 = tid >> 5, i4 = tid & 31;   // 16-group mapping (all 512)
  const int b0 = blockIdx.x * 2;
  const bool ident = (*FLG != 0);

  // prologue: W1 rows 1..128 -> LDS as k-quads [k4][hj]
  for (int idx = tid; idx < 8192; idx += TPB) {
    const int k4 = idx >> 8, h = idx & 255;
    float4 w;
    w.x = W1[(4*k4 + 1)*HH + h];
    w.y = W1[(4*k4 + 2)*HH + h];
    w.z = W1[(4*k4 + 3)*HH + h];
    w.w = W1[(4*k4 + 4)*HH + h];
    W1q[idx] = w;
  }
  const float w1t = W1[tid & 255];
  const float b1c = b1[tid & 255];
  const float b2i = b2[i];
  if (tid < 256) xs[tid] = x0[i];

  float lwloc = 0.f, u_reg = 0.f, nz = 0.f;

  for (int t = 0; t <= NS; ++t) {
    __syncthreads();                                   // [A] xs ready
    const float t0 = tsf(t);
    const float dt = tsf(t+1) - t0;
    const float sdt = sqrtf(dt);

    if (ident) {
      // ---------------- phase A: MLP-L1 (waves 0-3) || AT/PT matvec (4-7)
      if (tid < 256) {
        float a0 = t0*w1t, a1 = t0*w1t;
#pragma unroll
        for (int m = 0; m < 32; ++m) {
          const float4 w = W1q[m*256 + tid];
          a0 = fma4(w, xs4[m], a0);
          a1 = fma4(w, xs4[32 + m], a1);
        }
        hs[tid]       = tanhf(a0 + b1c);
        hs[256 + tid] = tanhf(a1 + b1c);
      } else if (t < NS) {
        const int tid2 = tid - 256;
        const int i2 = tid2 & 127, r = tid2 >> 7;
        noi[tid2] = noises[((size_t)t*BB + b0 + r)*DD + i2];
        const int kq2 = tid2 >> 5, i4b = tid2 & 31;
        if (kq2 < 4) {          // A@x partials (32-k slice)
          float4 x0a = make_float4(0,0,0,0), x1a = make_float4(0,0,0,0);
#pragma unroll
          for (int kk = 0; kk < 32; ++kk) {
            const int k = kq2*32 + kk;
            const float4 av = *(const float4*)&AT[k*DD + i4b*4];
            x0a = fma_s4(xs[k],       av, x0a);
            x1a = fma_s4(xs[128 + k], av, x1a);
          }
          scr4[kq2*64 + i4b]      = x0a;
          scr4[kq2*64 + 32 + i4b] = x1a;
        } else {                // P@x partials
          const int kg = kq2 - 4;
          float4 p0 = make_float4(0,0,0,0), p1 = make_float4(0,0,0,0);
#pragma unroll
          for (int kk = 0; kk < 32; ++kk) {
            const int k = kg*32 + kk;
            const float4 pv = *(const float4*)&PT[k*DD + i4b*4];
            p0 = fma_s4(xs[k],       pv, p0);
            p1 = fma_s4(xs[128 + k], pv, p1);
          }
          scr4[256 + kg*64 + i4b]      = p0;
          scr4[256 + kg*64 + 32 + i4b] = p1;
        }
      }
      __syncthreads();                                 // [B]
      // ---------------- phase B: MLP-L2 partials (0-3) || xa/yy reduce (4-7)
      if (tid < 256) {
        const int kq = tid >> 5, i4b = tid & 31;
        float4 c0 = make_float4(0,0,0,0), c1 = make_float4(0,0,0,0);
#pragma unroll
        for (int kk = 0; kk < 32; ++kk) {
          const int k = kq*32 + kk;
          const float4 w2v = *(const float4*)&W2[k*DD + i4b*4];
          c0 = fma_s4(hs[k],       w2v, c0);
          c1 = fma_s4(hs[256 + k], w2v, c1);
        }
        scr4[512 + kq*64 + i4b]      = c0;
        scr4[512 + kq*64 + 32 + i4b] = c1;
      } else if (t < NS) {
        const int tid2 = tid - 256;
        const int i2 = tid2 & 127, r = tid2 >> 7;
        float xa = 0.f, yy = 0.f;
#pragma unroll
        for (int g = 0; g < 4; ++g) {
          xa += scr[g*256 + r*128 + i2];
          yy += scr[1024 + g*256 + r*128 + i2];
        }
        scr[4096 + tid2] = xa;
        scr[4352 + tid2] = yy;
        lwloc -= 0.5f*dt*xs[tid2]*yy;
      }
      __syncthreads();                                 // [C]
      // ---------------- phase C: u, U store, wv
      if (tid < 256) {
        float nv = b2i;
#pragma unroll
        for (int g = 0; g < 8; ++g) nv += scr[2048 + g*256 + tid];
        u_reg = -nv;
        U[((size_t)t*BB + b0 + (tid >> 7))*DD + i] = u_reg;
        if (t < NS) {
          nz = noi[tid];
          wv[tid] = sdt*nz + dt*u_reg;
          lwloc += sdt*u_reg*nz - 0.5f*dt*u_reg*u_reg;
        }
      }
      if (t == NS) break;
      __syncthreads();                                 // [D]
      // ---------------- phase D: A@wv partials, all 8 waves (8-k slices)
      {
        float4 m0 = make_float4(0,0,0,0), m1 = make_float4(0,0,0,0);
#pragma unroll
        for (int kk = 0; kk < 8; ++kk) {
          const int k = kq16*8 + kk;
          const float4 av = *(const float4*)&AT[k*DD + i4*4];
          m0 = fma_s4(wv[k],       av, m0);
          m1 = fma_s4(wv[128 + k], av, m1);
        }
        scr4[kq16*64 + i4]      = m0;
        scr4[kq16*64 + 32 + i4] = m1;
      }
      __syncthreads();                                 // [E]
      // ---------------- phase E: combine, TL store, x update
      if (tid < 256) {
        const int r = tid >> 7;
        float mm = 0.f;
#pragma unroll
        for (int g = 0; g < 16; ++g) mm += scr[g*256 + tid];
        mm = -mm;                                      // M2 = -A
        const float xa = scr[4096 + tid];
        const float yy = scr[4352 + tid];
        const float xo = xs[tid];
        TL[(size_t)(t+1)*(BB*DD) + (size_t)(b0 + r)*DD + i] = dt*yy + mm;
        xs[tid] = xo + (xa + u_reg)*dt + sdt*nz;
      }
    } else {
      // =============== general sigma path (correctness; sigma != I) =======
      if (tid < 256) {
        float a0 = t0*w1t, a1 = t0*w1t;
#pragma unroll
        for (int m = 0; m < 32; ++m) {
          const float4 w = W1q[m*256 + tid];
          a0 = fma4(w, xs4[m], a0);
          a1 = fma4(w, xs4[32 + m], a1);
        }
        hs[tid]       = tanhf(a0 + b1c);
        hs[256 + tid] = tanhf(a1 + b1c);
      } else if (t < NS) {
        const int tid2 = tid - 256;
        const int i2 = tid2 & 127, r = tid2 >> 7;
        noi[tid2] = noises[((size_t)t*BB + b0 + r)*DD + i2];
        const int kq2 = tid2 >> 5, i4b = tid2 & 31;
        if (kq2 < 4) {
          float4 x0a = make_float4(0,0,0,0), x1a = make_float4(0,0,0,0);
#pragma unroll
          for (int kk = 0; kk < 32; ++kk) {
            const int k = kq2*32 + kk;
            const float4 av = *(const float4*)&AT[k*DD + i4b*4];
            x0a = fma_s4(xs[k],       av, x0a);
            x1a = fma_s4(xs[128 + k], av, x1a);
          }
          scr4[kq2*64 + i4b]      = x0a;
          scr4[kq2*64 + 32 + i4b] = x1a;
        } else {
          const int kg = kq2 - 4;
          float4 p0 = make_float4(0,0,0,0), p1 = make_float4(0,0,0,0);
#pragma unroll
          for (int kk = 0; kk < 32; ++kk) {
            const int k = kg*32 + kk;
            const float4 pv = *(const float4*)&PT[k*DD + i4b*4];
            p0 = fma_s4(xs[k],       pv, p0);
            p1 = fma_s4(xs[128 + k], pv, p1);
          }
          scr4[256 + kg*64 + i4b]      = p0;
          scr4[256 + kg*64 + 32 + i4b] = p1;
        }
      }
      __syncthreads();                                 // [B]
      if (tid < 256) {
        const int kq = tid >> 5, i4b = tid & 31;
        float4 c0 = make_float4(0,0,0,0), c1 = make_float4(0,0,0,0);
#pragma unroll
        for (int kk = 0; kk < 32; ++kk) {
          const int k = kq*32 + kk;
          const float4 w2v = *(const float4*)&W2[k*DD + i4b*4];
          c0 = fma_s4(hs[k],       w2v, c0);
          c1 = fma_s4(hs[256 + k], w2v, c1);
        }
        scr4[512 + kq*64 + i4b]      = c0;
        scr4[512 + kq*64 + 32 + i4b] = c1;
      } else if (t < NS) {
        const int tid2 = tid - 256;
        const int i2 = tid2 & 127, r = tid2 >> 7;
        float xa = 0.f, yy = 0.f;
#pragma unroll
        for (int g = 0; g < 4; ++g) {
          xa += scr[g*256 + r*128 + i2];
          yy += scr[1024 + g*256 + r*128 + i2];
        }
        scr[4096 + tid2] = xa;
        scr[4352 + tid2] = yy;
        lwloc -= 0.5f*dt*xs[tid2]*yy;
      }
      __syncthreads();                                 // [C] nv combine
      if (tid < 256) {
        float nv = b2i;
#pragma unroll
        for (int g = 0; g < 8; ++g) nv += scr[2048 + g*256 + tid];
        nvu[tid] = nv;
      }
      __syncthreads();                                 // [C2] nv@sigma
      if (tid < 256) {
        const int kq = tid >> 5, i4b = tid & 31;
        float4 s0 = make_float4(0,0,0,0), s1 = make_float4(0,0,0,0);
#pragma unroll
        for (int kk = 0; kk < 16; ++kk) {
          const int k = kq*16 + kk;
          const float4 gv = *(const float4*)&sigma[k*DD + i4b*4];
          s0 = fma_s4(nvu[k],       gv, s0);
          s1 = fma_s4(nvu[128 + k], gv, s1);
        }
        scr4[512 + kq*64 + i4b]      = s0;
        scr4[512 + kq*64 + 32 + i4b] = s1;
      }
      __syncthreads();                                 // [C3] u, U, wv
      if (tid < 256) {
        float s = 0.f;
#pragma unroll
        for (int g = 0; g < 8; ++g) s += scr[2048 + g*256 + tid];
        u_reg = -s;
        U[((size_t)t*BB + b0 + (tid >> 7))*DD + i] = u_reg;
        nvu[tid] = u_reg;    // now holds u
        if (t < NS) {
          nz = noi[tid];
          wv[tid] = sdt*nz + dt*u_reg;
          lwloc += sdt*u_reg*nz - 0.5f*dt*u_reg*u_reg;
        }
      }
      if (t == NS) break;
      __syncthreads();                                 // [D] M2@wv || SGT@u
      if (tid < 256) {
        const int kq = tid >> 5, i4b = tid & 31;
        float4 m0 = make_float4(0,0,0,0), m1 = make_float4(0,0,0,0);
#pragma unroll
        for (int kk = 0; kk < 16; ++kk) {
          const int k = kq*16 + kk;
          const float4 mv = *(const float4*)&M2T[k*DD + i4b*4];
          m0 = fma_s4(wv[k],       mv, m0);
          m1 = fma_s4(wv[128 + k], mv, m1);
        }
        scr4[512 + kq*64 + i4b]      = m0;
        scr4[512 + kq*64 + 32 + i4b] = m1;
      } else {
        const int tid2 = tid - 256;
        const int kq2 = tid2 >> 5, i4b = tid2 & 31;
        float4 s0 = make_float4(0,0,0,0), s1 = make_float4(0,0,0,0);
#pragma unroll
        for (int kk = 0; kk < 16; ++kk) {
          const int k = kq2*16 + kk;
          const float4 sv = *(const float4*)&SGT[k*DD + i4b*4];
          s0 = fma_s4(nvu[k],       sv, s0);
          s1 = fma_s4(nvu[128 + k], sv, s1);
        }
        scr4[kq2*64 + i4b]      = s0;
        scr4[kq2*64 + 32 + i4b] = s1;
      }
      __syncthreads();                                 // [D2] combine mm, us
      if (tid < 256) {
        float mm = 0.f;
#pragma unroll
        for (int g = 0; g < 8; ++g) mm += scr[2048 + g*256 + tid];
        wv[tid] = mm;                                  // wv repurposed = M2@wv
      } else {
        const int tid2 = tid - 256;
        float us = 0.f;
#pragma unroll
        for (int g = 0; g < 8; ++g) us += scr[g*256 + tid2];
        nvu[tid2] = us;                                // u@sigma^T
      }
      __syncthreads();                                 // [D3] SGT@noise (all)
      {
        float4 s0 = make_float4(0,0,0,0), s1 = make_float4(0,0,0,0);
#pragma unroll
        for (int kk = 0; kk < 8; ++kk) {
          const int k = kq16*8 + kk;
          const float4 sv = *(const float4*)&SGT[k*DD + i4*4];
          s0 = fma_s4(noi[k],       sv, s0);
          s1 = fma_s4(noi[128 + k], sv, s1);
        }
        scr4[kq16*64 + i4]      = s0;
        scr4[kq16*64 + 32 + i4] = s1;
      }
      __syncthreads();                                 // [E]
      if (tid < 256) {
        const int r = tid >> 7;
        float ns = 0.f;
#pragma unroll
        for (int g = 0; g < 16; ++g) ns += scr[g*256 + tid];
        const float mm = wv[tid];
        const float us = nvu[tid];
        const float xa = scr[4096 + tid];
        const float yy = scr[4352 + tid];
        const float xo = xs[tid];
        TL[(size_t)(t+1)*(BB*DD) + (size_t)(b0 + r)*DD + i] = dt*yy + mm;
        xs[tid] = xo + (xa + us)*dt + sdt*ns;
      }
    }
  }
  // --- epilogue: TGT = x_NS @ Q^T, WGT = exp(lw - 0.5 x^T Q x)
  __syncthreads();
  {
    float4 q0 = make_float4(0,0,0,0), q1 = make_float4(0,0,0,0);
#pragma unroll
    for (int kk = 0; kk < 8; ++kk) {
      const int k = kq16*8 + kk;
      const float4 qv = *(const float4*)&QT[k*DD + i4*4];
      q0 = fma_s4(xs[k],       qv, q0);
      q1 = fma_s4(xs[128 + k], qv, q1);
    }
    scr4[kq16*64 + i4]      = q0;
    scr4[kq16*64 + 32 + i4] = q1;
  }
  __syncthreads();
  float qloc = 0.f;
  if (tid < 256) {
    const int r = tid >> 7;
    float tt = 0.f;
#pragma unroll
    for (int g = 0; g < 16; ++g) tt += scr[g*256 + tid];
    TGT[(b0 + r)*DD + i] = tt;
    qloc = xs[tid]*tt;
  }
  const float rq = wave_red(qloc);
  const float rl = wave_red(lwloc);
  if ((tid & 63) == 0) { red[tid>>6] = rq; red[8 + (tid>>6)] = rl; }
  __syncthreads();
  if (tid == 0 || tid == 128) {
    const int r = tid >> 7;
    const float qf = red[2*r] + red[2*r + 1];
    // lw contributions: row r lives in waves {2r, 2r+1, 4+2r, 4+2r+1}
    const float lw = red[8 + 2*r] + red[8 + 2*r + 1]
                   + red[8 + 4 + 2*r] + red[8 + 4 + 2*r + 1];
    WGT[b0 + r] = expf(lw - 0.5f*qf);
  }
}

// ---- suffix scan over t (64k independent scans) + fused objective (ident)
__global__ __launch_bounds__(256) void k_scan(
    const float* __restrict__ TGT, const float* __restrict__ WGT,
    const float* __restrict__ U, float* __restrict__ TL,
    const int* __restrict__ FLG, float* __restrict__ PART_S)
{
  const int tid = threadIdx.x;
  const int bi = blockIdx.x*256 + tid;
  const int b = bi >> 7;
  const bool id = (*FLG != 0);
  const float w = WGT[b];
  float lst = TGT[bi];
  float obj = 0.f;
  if (id) { const float d = lst + U[(size_t)NS*(BB*DD) + bi]; obj = w*d*d; }
#pragma unroll 4
  for (int t = NS; t >= 1; --t) {
    const float v = TL[(size_t)t*(BB*DD) + bi];
    if (!id) TL[(size_t)t*(BB*DD) + bi] = lst;
    lst += v;
    if (id) { const float d = lst + U[(size_t)(t-1)*(BB*DD) + bi]; obj += w*d*d; }
  }
  if (!id) TL[bi] = lst;
  __shared__ float r4[4];
  const float s = wave_red(obj);
  if ((tid & 63) == 0) r4[tid >> 6] = s;
  __syncthreads();
  if (tid == 0) PART_S[blockIdx.x] = id ? (r4[0]+r4[1]+r4[2]+r4[3]) : 0.f;
}

// ---- general-sigma objective (no-op when sigma == I)
__global__ __launch_bounds__(256) void k_obj(
    const float* __restrict__ SGC, const float* __restrict__ TL,
    const float* __restrict__ U, const float* __restrict__ WGT,
    const int* __restrict__ FLG, float* __restrict__ PART_O)
{
  const int blk = blockIdx.x;
  if (*FLG != 0) { if (threadIdx.x == 0) PART_O[blk] = 0.f; return; }
  const int t = blk >> 6, bg = blk & 63;
  __shared__ __align__(16) float ls[8][132];
  __shared__ __align__(16) float us[8][128];
  __shared__ __align__(16) float pD[2][8][128];
  __shared__ float wg[8];
  __shared__ float r4[4];
  const int tid = threadIdx.x;
  const int i = tid & 127, h = tid >> 7;
  for (int idx = tid; idx < 8*128; idx += 256) {
    const int rr = idx >> 7, k = idx & 127;
    ls[rr][k] = TL[(size_t)t*(BB*DD) + (size_t)(bg*8+rr)*DD + k];
    us[rr][k] = U [(size_t)t*(BB*DD) + (size_t)(bg*8+rr)*DD + k];
  }
  if (tid < 8) wg[tid] = WGT[bg*8 + tid];
  __syncthreads();
  const float* grow = SGC + i*DD + h*64;
#pragma unroll
  for (int rr = 0; rr < 8; ++rr) {
    float a = 0.f;
#pragma unroll
    for (int it = 0; it < 16; ++it) {
      float4 gv = *(const float4*)(grow + it*4);
      float4 l4 = *(const float4*)&ls[rr][h*64 + it*4];
      a = fma4(gv, l4, a);
    }
    pD[h][rr][i] = a;
  }
  __syncthreads();
  float obj = 0.f;
#pragma unroll
  for (int p = 0; p < 4; ++p) {
    const int rr = h*4 + p;
    const float d = pD[0][rr][i] + pD[1][rr][i] + us[rr][i];
    obj += wg[rr]*d*d;
  }
  const float s = wave_red(obj);
  if ((tid & 63) == 0) r4[tid >> 6] = s;
  __syncthreads();
  if (tid == 0) PART_O[blk] = r4[0]+r4[1]+r4[2]+r4[3];
}

__global__ __launch_bounds__(256) void k_fin(
    const float* __restrict__ PART_S, const float* __restrict__ PART_O,
    float* __restrict__ out)
{
  const int tid = threadIdx.x;
  float s = PART_S[tid];
  for (int idx = tid; idx < NPO; idx += 256) s += PART_O[idx];
  __shared__ float r4[4];
  const float v = wave_red(s);
  if ((tid & 63) == 0) r4[tid >> 6] = v;
  __syncthreads();
  if (tid == 0) out[0] = (r4[0]+r4[1]+r4[2]+r4[3]) * (1.0f/((float)(NS+1)*(float)BB));
}

extern "C" void kernel_launch(void* const* d_in, const int* in_sizes, int n_in,
                              void* d_out, int out_size, void* d_ws, size_t ws_size,
                              hipStream_t stream) {
  (void)in_sizes; (void)n_in; (void)out_size; (void)ws_size;
  const float* x0     = (const float*)d_in[0];
  const float* sigma  = (const float*)d_in[1];
  const float* A      = (const float*)d_in[2];
  const float* P      = (const float*)d_in[3];
  const float* Q      = (const float*)d_in[4];
  const float* W1     = (const float*)d_in[5];
  const float* b1     = (const float*)d_in[6];
  const float* W2     = (const float*)d_in[7];
  const float* b2     = (const float*)d_in[8];
  const float* noises = (const float*)d_in[9];

  float* ws = (float*)d_ws;
  const size_t SL = (size_t)BB*DD;
  float* TL     = ws;
  float* U      = TL + (size_t)(NS+1)*SL;
  float* TGT    = U  + (size_t)(NS+1)*SL;
  float* WGT    = TGT + SL;
  float* ATm    = WGT + BB;
  float* PTm    = ATm + (size_t)DD*DD;
  float* QTm    = PTm + (size_t)DD*DD;
  float* SGTm   = QTm + (size_t)DD*DD;
  float* M2T    = SGTm + (size_t)DD*DD;
  float* SGC    = M2T + (size_t)DD*DD;
  float* SIT    = SGC + (size_t)DD*DD;
  float* AUG    = SIT + (size_t)DD*DD;
  float* PART_S = AUG + (size_t)DD*256;
  float* PART_O = PART_S + 256;
  int*   FLG    = (int*)(PART_O + NPO);
  float* out    = (float*)d_out;

  (void)hipFuncSetAttribute((const void*)k_rollout,
                            hipFuncAttributeMaxDynamicSharedMemorySize, SMEM_BYTES);

  k_pre1<<<1, 256, 0, stream>>>(sigma, SIT, AUG, FLG);
  k_pre2<<<32, 256, 0, stream>>>(A, P, Q, sigma, SIT, FLG,
                                 ATm, PTm, QTm, SGTm, M2T, SGC);
  k_rollout<<<NBLK, TPB, SMEM_BYTES, stream>>>(x0, sigma, W1, b1, W2, b2, noises,
                                               ATm, PTm, QTm, SGTm, M2T, FLG,
                                               U, TL, TGT, WGT);
  k_scan<<<(BB*DD)/256, 256, 0, stream>>>(TGT, WGT, U, TL, FLG, PART_S);
  k_obj<<<NPO, 256, 0, stream>>>(SGC, TL, U, WGT, FLG, PART_O);
  k_fin<<<1, 256, 0, stream>>>(PART_S, PART_O, out);
}

// Round 10
// 2524.986 us; speedup vs baseline: 3.7109x; 3.7109x over previous
//
#include <hip/hip_runtime.h>
#include <math.h>

#define DD 128
#define HH 256
#define NS 300
#define BB 512
#define NBLK 256   // rollout blocks (2 rows each)
#define TPB 512
#define NPO (301*64)

__device__ __forceinline__ float tsf(int t){ return (float)((double)t*(1.0/(double)NS)); }

__device__ __forceinline__ float wave_red(float v){
#pragma unroll
  for(int o=32;o>0;o>>=1) v += __shfl_down(v,o);
  return v;
}
__device__ __forceinline__ float fma4(float4 a, float4 b, float acc){
  acc = fmaf(a.x,b.x,acc); acc = fmaf(a.y,b.y,acc);
  acc = fmaf(a.z,b.z,acc); acc = fmaf(a.w,b.w,acc); return acc;
}

// ---- pre1: identity flag + (general) Gauss-Jordan inverse -> SIT = sigma^-T
__global__ __launch_bounds__(256) void k_pre1(
    const float* __restrict__ sigma,
    float* __restrict__ SIT, float* __restrict__ AUG, int* __restrict__ FLG)
{
  const int j = threadIdx.x;
  __shared__ int s_ok; __shared__ int s_p; __shared__ float s_fac[DD];
  if (j == 0) s_ok = 1;
  __syncthreads();
  bool ok = true;
  for (int idx = j; idx < DD*DD; idx += 256) {
    const int r = idx >> 7, c = idx & 127;
    if (sigma[idx] != (r==c ? 1.f : 0.f)) ok = false;
  }
  if (!ok) s_ok = 0;
  __syncthreads();
  const bool ident = (s_ok != 0);
  if (j == 0) *FLG = ident ? 1 : 0;
  if (ident) {
    for (int idx = j; idx < DD*DD; idx += 256) {
      const int r = idx >> 7, c = idx & 127;
      SIT[idx] = (r==c) ? 1.f : 0.f;
    }
    return;
  }
  for (int idx = j; idx < DD*256; idx += 256) {
    const int r = idx >> 8, c = idx & 255;
    AUG[idx] = (c < DD) ? sigma[r*DD + c] : ((c-DD)==r ? 1.f : 0.f);
  }
  __syncthreads();
  for (int c = 0; c < DD; ++c) {
    if (j == 0) {
      int p = c; float best = fabsf(AUG[c*256 + c]);
      for (int r2 = c+1; r2 < DD; ++r2) {
        const float v = fabsf(AUG[r2*256 + c]);
        if (v > best) { best = v; p = r2; }
      }
      s_p = p;
    }
    __syncthreads();
    const int p = s_p;
    if (p != c) {
      const float tmp = AUG[c*256 + j];
      AUG[c*256 + j] = AUG[p*256 + j];
      AUG[p*256 + j] = tmp;
    }
    __syncthreads();
    const float pd = AUG[c*256 + c];
    const float rowv = AUG[c*256 + j];
    __syncthreads();
    AUG[c*256 + j] = rowv / pd;
    if (j < DD) s_fac[j] = (j == c) ? 0.f : AUG[j*256 + c];
    __syncthreads();
    const float prj = AUG[c*256 + j];
    for (int r2 = 0; r2 < DD; ++r2) {
      if (r2 != c) AUG[r2*256 + j] -= s_fac[r2] * prj;
    }
    __syncthreads();
  }
  for (int idx = j; idx < DD*DD; idx += 256) {
    const int j2 = idx >> 7, k = idx & 127;
    SIT[idx] = AUG[k*256 + DD + j2];   // sigma^-T[j2][k]
  }
}

// ---- pre2: quad-interleaved coalesced weight layouts.
// W1L[(k4*256+hj)*4+j] = W1[(4k4+1+j)][hj]      (k4<32)
// W2L[(k4*128+i)*4+j]  = W2[(4k4+j)][i]          (k4<64)
// AL/PL/QL/STL[(k4*128+i)*4+j] = M[i][4k4+j]     (k4<32; STL from sigma)
// SL[(k4*128+i)*4+j]   = sigma[4k4+j][i]
// ML = M2 = -(A @ sigma^-T) in AL-style layout; SGC[i][k] = sigma[k][i]
__global__ __launch_bounds__(256) void k_pre2(
    const float* __restrict__ W1, const float* __restrict__ W2,
    const float* __restrict__ A, const float* __restrict__ P,
    const float* __restrict__ Q, const float* __restrict__ sigma,
    const float* __restrict__ SIT, const int* __restrict__ FLG,
    float* __restrict__ W1L, float* __restrict__ W2L,
    float* __restrict__ AL, float* __restrict__ PL,
    float* __restrict__ ML, float* __restrict__ SL,
    float* __restrict__ STL, float* __restrict__ QL,
    float* __restrict__ SGC)
{
  const int g = blockIdx.x*256 + threadIdx.x;
  const int gs = gridDim.x*256;
  const bool ident = (*FLG != 0);
  for (int idx = g; idx < 32*256; idx += gs) {
    const int k4 = idx >> 8, hj = idx & 255;
#pragma unroll
    for (int j = 0; j < 4; ++j)
      W1L[idx*4 + j] = W1[(4*k4 + 1 + j)*HH + hj];
  }
  for (int idx = g; idx < 64*128; idx += gs) {
    const int k4 = idx >> 7, i = idx & 127;
#pragma unroll
    for (int j = 0; j < 4; ++j)
      W2L[idx*4 + j] = W2[(4*k4 + j)*DD + i];
  }
  for (int idx = g; idx < 32*128; idx += gs) {
    const int k4 = idx >> 7, i = idx & 127;
#pragma unroll
    for (int j = 0; j < 4; ++j) {
      AL [idx*4 + j] = A[i*DD + 4*k4 + j];
      PL [idx*4 + j] = P[i*DD + 4*k4 + j];
      QL [idx*4 + j] = Q[i*DD + 4*k4 + j];
      STL[idx*4 + j] = sigma[i*DD + 4*k4 + j];
      SL [idx*4 + j] = sigma[(4*k4 + j)*DD + i];
      float m;
      if (ident) m = -A[i*DD + 4*k4 + j];
      else {
        float acc = 0.f;
        for (int jj = 0; jj < DD; ++jj)
          acc = fmaf(A[i*DD + jj], SIT[jj*DD + 4*k4 + j], acc);
        m = -acc;
      }
      ML[idx*4 + j] = m;
    }
  }
  for (int idx = g; idx < DD*DD; idx += gs) {
    const int i2 = idx >> 7, k = idx & 127;
    SGC[idx] = sigma[k*DD + i2];
  }
}

// ---- rollout: 256 blocks x 512 threads, 2 rows/block. Round-2 structure
// (all phases full-width, no register residency, 6 barriers) with every
// streamed matrix in a coalesced quad layout: lane index is innermost, so
// each 64-lane load touches 16 cache lines instead of 64.
__global__ __launch_bounds__(TPB) void k_rollout(
    const float* __restrict__ x0,
    const float* __restrict__ W1, const float* __restrict__ b1,
    const float* __restrict__ b2, const float* __restrict__ noises,
    const float* __restrict__ W1L, const float* __restrict__ W2L,
    const float* __restrict__ AL, const float* __restrict__ PL,
    const float* __restrict__ ML, const float* __restrict__ SL,
    const float* __restrict__ STL, const float* __restrict__ QL,
    const int* __restrict__ FLG,
    float* __restrict__ U, float* __restrict__ TL,
    float* __restrict__ TGT, float* __restrict__ WGT)
{
  __shared__ __align__(16) float xs[2][128];
  __shared__ __align__(16) float hs[2][256];
  __shared__ __align__(16) float noi[2][128];
  __shared__ __align__(16) float nvs[2][128];
  __shared__ __align__(16) float uu[2][128];
  __shared__ __align__(16) float wv[2][128];
  __shared__ __align__(16) float p2[2][2][256];
  __shared__ __align__(16) float p4[4][2][128];
  __shared__ __align__(16) float pm3[3][4][2][128];
  __shared__ float red[16];

  const float4* W1L4 = (const float4*)W1L;
  const float4* W2L4 = (const float4*)W2L;
  const float4* AL4  = (const float4*)AL;
  const float4* PL4  = (const float4*)PL;
  const float4* ML4  = (const float4*)ML;
  const float4* SL4  = (const float4*)SL;
  const float4* STL4 = (const float4*)STL;
  const float4* QL4  = (const float4*)QL;
  float4* xs4  = (float4*)&xs[0][0];    // row r: quad offset r*32
  float4* hs4  = (float4*)&hs[0][0];    // row r: quad offset r*64
  float4* wv4  = (float4*)&wv[0][0];
  float4* nvs4 = (float4*)&nvs[0][0];
  float4* uu4  = (float4*)&uu[0][0];
  float4* noi4 = (float4*)&noi[0][0];
  float* p2f = &p2[0][0][0];
  float* p4f = &p4[0][0][0];
  float* pA  = &pm3[0][0][0][0];
  float* pP  = &pm3[1][0][0][0];
  float* pM  = &pm3[2][0][0][0];

  const int tid = threadIdx.x;
  const int hj = tid & 255, hg = tid >> 8;   // layer-1 mapping
  const int i  = tid & 127, q  = tid >> 7;   // layer-2 / matvec mapping
  const int wid = tid >> 6;
  const int b0 = blockIdx.x * 2;
  const bool ident = (*FLG != 0);
  const float w1t = (hg == 0) ? W1[hj] : 0.f;
  const float b1c = b1[hj];
  const float b2i = b2[i];

  if (tid < 256) xs[tid >> 7][tid & 127] = x0[tid & 127];

  float lwloc = 0.f, u_reg = 0.f, nz = 0.f;

  for (int t = 0; t <= NS; ++t) {
    __syncthreads();                                   // [A] xs ready
    const float t0 = tsf(t);
    const float dt = tsf(t+1) - t0;
    const float sdt = sqrtf(dt);
    nz = 0.f;
    if (q < 2 && t < NS) {
      nz = noises[((size_t)t*BB + b0 + q)*DD + i];
      noi[q][i] = nz;
    }
    // --- MLP layer 1: thread (hj,hg) half-dot; coalesced W1L reads
    {
      float a0 = t0*w1t, a1 = t0*w1t;
#pragma unroll
      for (int m = 0; m < 16; ++m) {
        const float4 w = W1L4[(hg*16 + m)*256 + hj];
        a0 = fma4(w, xs4[hg*16 + m], a0);
        a1 = fma4(w, xs4[32 + hg*16 + m], a1);
      }
      p2[hg][0][hj] = a0; p2[hg][1][hj] = a1;
    }
    __syncthreads();                                   // [B]
    {
      const int rr = tid >> 8, cc = tid & 255;
      hs[rr][cc] = tanhf(p2[0][rr][cc] + p2[1][rr][cc] + b1c);
    }
    __syncthreads();                                   // [C]
    // --- MLP layer 2: thread (i,q) quarter-dot; coalesced W2L reads
    {
      float c0 = 0.f, c1 = 0.f;
#pragma unroll
      for (int m = 0; m < 16; ++m) {
        const float4 w2 = W2L4[(q*16 + m)*128 + i];
        c0 = fma4(w2, hs4[q*16 + m], c0);
        c1 = fma4(w2, hs4[64 + q*16 + m], c1);
      }
      p4[q][0][i] = c0; p4[q][1][i] = c1;
    }
    __syncthreads();                                   // [D]
    if (ident) {
      if (q < 2) {
        const float nv = p4[0][q][i] + p4[1][q][i] + p4[2][q][i] + p4[3][q][i] + b2i;
        u_reg = -nv;
        U[((size_t)t*BB + b0 + q)*DD + i] = u_reg;
        wv[q][i] = sdt*nz + dt*u_reg;
        if (t < NS) lwloc += sdt*u_reg*nz - 0.5f*dt*u_reg*u_reg;
      }
    } else {
      if (q < 2) {
        nvs[q][i] = p4[0][q][i] + p4[1][q][i] + p4[2][q][i] + p4[3][q][i] + b2i;
      }
      __syncthreads();                                 // [D2] u = -nv @ sigma
      {
        float s0 = 0.f, s1 = 0.f;
#pragma unroll
        for (int m = 0; m < 8; ++m) {
          const float4 gv = SL4[(q*8 + m)*128 + i];
          s0 = fma4(gv, nvs4[q*8 + m], s0);
          s1 = fma4(gv, nvs4[32 + q*8 + m], s1);
        }
        pA[q*256 + i] = s0; pA[q*256 + 128 + i] = s1;
      }
      __syncthreads();                                 // [D3]
      if (q < 2) {
        u_reg = -(pA[q*128 + i] + pA[256 + q*128 + i]
                + pA[512 + q*128 + i] + pA[768 + q*128 + i]);
        uu[q][i] = u_reg;
        U[((size_t)t*BB + b0 + q)*DD + i] = u_reg;
        wv[q][i] = sdt*nz + dt*u_reg;
        if (t < NS) lwloc += sdt*u_reg*nz - 0.5f*dt*u_reg*u_reg;
      }
    }
    if (t == NS) break;
    __syncthreads();                                   // [E] wv (and uu) ready
    // --- matvecs, coalesced AL/PL (ident: M2@wv = -(A@wv) reuses AL stream)
    {
      float aA0=0,aA1=0,aP0=0,aP1=0,aM0=0,aM1=0;
      if (ident) {
#pragma unroll
        for (int m = 0; m < 8; ++m) {
          const float4 av = AL4[(q*8 + m)*128 + i];
          const float4 pv = PL4[(q*8 + m)*128 + i];
          const float4 x0v = xs4[q*8 + m];
          const float4 x1v = xs4[32 + q*8 + m];
          const float4 w0v = wv4[q*8 + m];
          const float4 w1v = wv4[32 + q*8 + m];
          aA0 = fma4(av, x0v, aA0); aA1 = fma4(av, x1v, aA1);
          aP0 = fma4(pv, x0v, aP0); aP1 = fma4(pv, x1v, aP1);
          aM0 = fma4(av, w0v, aM0); aM1 = fma4(av, w1v, aM1);
        }
        aM0 = -aM0; aM1 = -aM1;
      } else {
#pragma unroll
        for (int m = 0; m < 8; ++m) {
          const float4 av = AL4[(q*8 + m)*128 + i];
          const float4 pv = PL4[(q*8 + m)*128 + i];
          const float4 mv = ML4[(q*8 + m)*128 + i];
          const float4 x0v = xs4[q*8 + m];
          const float4 x1v = xs4[32 + q*8 + m];
          const float4 w0v = wv4[q*8 + m];
          const float4 w1v = wv4[32 + q*8 + m];
          aA0 = fma4(av, x0v, aA0); aA1 = fma4(av, x1v, aA1);
          aP0 = fma4(pv, x0v, aP0); aP1 = fma4(pv, x1v, aP1);
          aM0 = fma4(mv, w0v, aM0); aM1 = fma4(mv, w1v, aM1);
        }
      }
      pA[q*256 + i] = aA0; pA[q*256 + 128 + i] = aA1;
      pP[q*256 + i] = aP0; pP[q*256 + 128 + i] = aP1;
      pM[q*256 + i] = aM0; pM[q*256 + 128 + i] = aM1;
      if (!ident) {
        float su0=0,su1=0,sn0=0,sn1=0;
#pragma unroll
        for (int m = 0; m < 8; ++m) {
          const float4 sv = STL4[(q*8 + m)*128 + i];
          su0 = fma4(sv, uu4[q*8 + m],  su0);
          su1 = fma4(sv, uu4[32 + q*8 + m], su1);
          sn0 = fma4(sv, noi4[q*8 + m], sn0);
          sn1 = fma4(sv, noi4[32 + q*8 + m], sn1);
        }
        p2f[q*256 + i] = su0; p2f[q*256 + 128 + i] = su1;
        p4f[q*256 + i] = sn0; p4f[q*256 + 128 + i] = sn1;
      }
    }
    __syncthreads();                                   // [F]
    if (q < 2) {
      const float xo = xs[q][i];
      const float xa = pA[q*128+i] + pA[256+q*128+i] + pA[512+q*128+i] + pA[768+q*128+i];
      const float yy = pP[q*128+i] + pP[256+q*128+i] + pP[512+q*128+i] + pP[768+q*128+i];
      const float mm = pM[q*128+i] + pM[256+q*128+i] + pM[512+q*128+i] + pM[768+q*128+i];
      float usv, nsv;
      if (ident) { usv = u_reg; nsv = nz; }
      else {
        usv = p2f[q*128+i] + p2f[256+q*128+i] + p2f[512+q*128+i] + p2f[768+q*128+i];
        nsv = p4f[q*128+i] + p4f[256+q*128+i] + p4f[512+q*128+i] + p4f[768+q*128+i];
      }
      TL[(size_t)(t+1)*(BB*DD) + (size_t)(b0 + q)*DD + i] = dt*yy + mm;
      xs[q][i] = xo + (xa + usv)*dt + sdt*nsv;
      lwloc -= 0.5f*dt*xo*yy;
    }
  }
  // --- epilogue: TGT = x_NS @ Q^T, WGT = exp(lw - 0.5 x^T Q x)
  __syncthreads();
  {
    float g0 = 0.f, g1 = 0.f;
#pragma unroll
    for (int m = 0; m < 8; ++m) {
      const float4 qv = QL4[(q*8 + m)*128 + i];
      g0 = fma4(qv, xs4[q*8 + m], g0);
      g1 = fma4(qv, xs4[32 + q*8 + m], g1);
    }
    pA[q*256 + i] = g0; pA[q*256 + 128 + i] = g1;
  }
  __syncthreads();
  float qloc = 0.f;
  if (q < 2) {
    const float tt = pA[q*128+i] + pA[256+q*128+i] + pA[512+q*128+i] + pA[768+q*128+i];
    TGT[(b0 + q)*DD + i] = tt;
    qloc = xs[q][i]*tt;
  }
  const float rq = wave_red(qloc);
  const float rl = wave_red(lwloc);
  if ((tid & 63) == 0) { red[wid] = rq; red[8 + wid] = rl; }
  __syncthreads();
  if (tid < 2) {
    const float qf = red[2*tid] + red[2*tid + 1];
    const float lw = red[8 + 2*tid] + red[8 + 2*tid + 1];
    WGT[b0 + tid] = expf(lw - 0.5f*qf);
  }
}

// ---- suffix scan over t (64k independent scans) + fused objective (ident)
__global__ __launch_bounds__(256) void k_scan(
    const float* __restrict__ TGT, const float* __restrict__ WGT,
    const float* __restrict__ U, float* __restrict__ TL,
    const int* __restrict__ FLG, float* __restrict__ PART_S)
{
  const int tid = threadIdx.x;
  const int bi = blockIdx.x*256 + tid;
  const int b = bi >> 7;
  const bool id = (*FLG != 0);
  const float w = WGT[b];
  float lst = TGT[bi];
  float obj = 0.f;
  if (id) { const float d = lst + U[(size_t)NS*(BB*DD) + bi]; obj = w*d*d; }
#pragma unroll 4
  for (int t = NS; t >= 1; --t) {
    const float v = TL[(size_t)t*(BB*DD) + bi];
    if (!id) TL[(size_t)t*(BB*DD) + bi] = lst;
    lst += v;
    if (id) { const float d = lst + U[(size_t)(t-1)*(BB*DD) + bi]; obj += w*d*d; }
  }
  if (!id) TL[bi] = lst;
  __shared__ float r4[4];
  const float s = wave_red(obj);
  if ((tid & 63) == 0) r4[tid >> 6] = s;
  __syncthreads();
  if (tid == 0) PART_S[blockIdx.x] = id ? (r4[0]+r4[1]+r4[2]+r4[3]) : 0.f;
}

// ---- general-sigma objective (no-op when sigma == I)
__global__ __launch_bounds__(256) void k_obj(
    const float* __restrict__ SGC, const float* __restrict__ TL,
    const float* __restrict__ U, const float* __restrict__ WGT,
    const int* __restrict__ FLG, float* __restrict__ PART_O)
{
  const int blk = blockIdx.x;
  if (*FLG != 0) { if (threadIdx.x == 0) PART_O[blk] = 0.f; return; }
  const int t = blk >> 6, bg = blk & 63;
  __shared__ __align__(16) float ls[8][132];
  __shared__ __align__(16) float us[8][128];
  __shared__ __align__(16) float pD[2][8][128];
  __shared__ float wg[8];
  __shared__ float r4[4];
  const int tid = threadIdx.x;
  const int i = tid & 127, h = tid >> 7;
  for (int idx = tid; idx < 8*128; idx += 256) {
    const int rr = idx >> 7, k = idx & 127;
    ls[rr][k] = TL[(size_t)t*(BB*DD) + (size_t)(bg*8+rr)*DD + k];
    us[rr][k] = U [(size_t)t*(BB*DD) + (size_t)(bg*8+rr)*DD + k];
  }
  if (tid < 8) wg[tid] = WGT[bg*8 + tid];
  __syncthreads();
  const float* grow = SGC + i*DD + h*64;
#pragma unroll
  for (int rr = 0; rr < 8; ++rr) {
    float a = 0.f;
#pragma unroll
    for (int it = 0; it < 16; ++it) {
      float4 gv = *(const float4*)(grow + it*4);
      float4 l4 = *(const float4*)&ls[rr][h*64 + it*4];
      a = fma4(gv, l4, a);
    }
    pD[h][rr][i] = a;
  }
  __syncthreads();
  float obj = 0.f;
#pragma unroll
  for (int p = 0; p < 4; ++p) {
    const int rr = h*4 + p;
    const float d = pD[0][rr][i] + pD[1][rr][i] + us[rr][i];
    obj += wg[rr]*d*d;
  }
  const float s = wave_red(obj);
  if ((tid & 63) == 0) r4[tid >> 6] = s;
  __syncthreads();
  if (tid == 0) PART_O[blk] = r4[0]+r4[1]+r4[2]+r4[3];
}

__global__ __launch_bounds__(256) void k_fin(
    const float* __restrict__ PART_S, const float* __restrict__ PART_O,
    float* __restrict__ out)
{
  const int tid = threadIdx.x;
  float s = PART_S[tid];
  for (int idx = tid; idx < NPO; idx += 256) s += PART_O[idx];
  __shared__ float r4[4];
  const float v = wave_red(s);
  if ((tid & 63) == 0) r4[tid >> 6] = v;
  __syncthreads();
  if (tid == 0) out[0] = (r4[0]+r4[1]+r4[2]+r4[3]) * (1.0f/((float)(NS+1)*(float)BB));
}

extern "C" void kernel_launch(void* const* d_in, const int* in_sizes, int n_in,
                              void* d_out, int out_size, void* d_ws, size_t ws_size,
                              hipStream_t stream) {
  (void)in_sizes; (void)n_in; (void)out_size; (void)ws_size;
  const float* x0     = (const float*)d_in[0];
  const float* sigma  = (const float*)d_in[1];
  const float* A      = (const float*)d_in[2];
  const float* P      = (const float*)d_in[3];
  const float* Q      = (const float*)d_in[4];
  const float* W1     = (const float*)d_in[5];
  const float* b1     = (const float*)d_in[6];
  const float* W2     = (const float*)d_in[7];
  const float* b2     = (const float*)d_in[8];
  const float* noises = (const float*)d_in[9];

  float* ws = (float*)d_ws;
  const size_t SL_ = (size_t)BB*DD;
  float* TL     = ws;
  float* U      = TL + (size_t)(NS+1)*SL_;
  float* TGT    = U  + (size_t)(NS+1)*SL_;
  float* WGT    = TGT + SL_;
  float* W1L    = WGT + BB;
  float* W2L    = W1L + 32*256*4;
  float* ALm    = W2L + 64*128*4;
  float* PLm    = ALm + 32*128*4;
  float* MLm    = PLm + 32*128*4;
  float* SLm    = MLm + 32*128*4;
  float* STLm   = SLm + 32*128*4;
  float* QLm    = STLm + 32*128*4;
  float* SGC    = QLm + 32*128*4;
  float* SIT    = SGC + (size_t)DD*DD;
  float* AUG    = SIT + (size_t)DD*DD;
  float* PART_S = AUG + (size_t)DD*256;
  float* PART_O = PART_S + 256;
  int*   FLG    = (int*)(PART_O + NPO);
  float* out    = (float*)d_out;

  k_pre1<<<1, 256, 0, stream>>>(sigma, SIT, AUG, FLG);
  k_pre2<<<64, 256, 0, stream>>>(W1, W2, A, P, Q, sigma, SIT, FLG,
                                 W1L, W2L, ALm, PLm, MLm, SLm, STLm, QLm, SGC);
  k_rollout<<<NBLK, TPB, 0, stream>>>(x0, W1, b1, b2, noises,
                                      W1L, W2L, ALm, PLm, MLm, SLm, STLm, QLm,
                                      FLG, U, TL, TGT, WGT);
  k_scan<<<(BB*DD)/256, 256, 0, stream>>>(TGT, WGT, U, TL, FLG, PART_S);
  k_obj<<<NPO, 256, 0, stream>>>(SGC, TL, U, WGT, FLG, PART_O);
  k_fin<<<1, 256, 0, stream>>>(PART_S, PART_O, out);
}